// Round 10
// baseline (216.709 us; speedup 1.0000x reference)
//
#include <hip/hip_runtime.h>

typedef __attribute__((ext_vector_type(8))) short bf16x8;
typedef __attribute__((ext_vector_type(4))) float f32x4;

__device__ __forceinline__ unsigned short f2bf(float f) {
  union { float f; unsigned u; } v; v.f = f;
  unsigned r = v.u + 0x7fffu + ((v.u >> 16) & 1u);
  return (unsigned short)(r >> 16);
}

// ================= merged prep: cvt_x | transpose A | transpose B | compact =================
__global__ __launch_bounds__(256)
void prep_kernel(const float* __restrict__ x, unsigned short* __restrict__ x_bf,
                 const float* __restrict__ A, unsigned short* __restrict__ A_t,
                 const float* __restrict__ B, unsigned short* __restrict__ B_t,
                 const int* __restrict__ mask, int* __restrict__ rows,
                 int* __restrict__ counts) {
  __shared__ float tbuf[32][33];
  __shared__ int cnt, mcnt;
  const int bid = blockIdx.x;
  const int t = threadIdx.x;

  if (bid < 4096) {  // ---- cvt_x: f32 -> bf16 ----
    int i = bid * 256 + t;
    float4 v = ((const float4*)x)[i];
    ushort4 o; o.x = f2bf(v.x); o.y = f2bf(v.y); o.z = f2bf(v.z); o.w = f2bf(v.w);
    ((ushort4*)x_bf)[i] = o;
    return;
  }
  if (bid < 20480) {  // ---- transpose+convert A or B ----
    const float* in; unsigned short* out; int R, C, cx, ry, z;
    if (bid < 12288) {  // A: [16][1024][512] -> [16][512][1024]
      int local = (bid - 4096) & 511; z = (bid - 4096) >> 9;
      R = 1024; C = 512; cx = local & 15; ry = local >> 4;
      in = A; out = A_t;
    } else {            // B: [16][512][1024] -> [16][1024][512]
      int local = (bid - 12288) & 511; z = (bid - 12288) >> 9;
      R = 512; C = 1024; cx = local & 31; ry = local >> 5;
      in = B; out = B_t;
    }
    size_t eo = (size_t)z * R * C;
    const float* src = in + eo;
    unsigned short* dst = out + eo;
    int c0 = cx * 32, r0 = ry * 32;
    int tx = t & 31, ty = t >> 5;  // (32,8)
#pragma unroll
    for (int i = 0; i < 32; i += 8)
      tbuf[ty + i][tx] = src[(size_t)(r0 + ty + i) * C + (c0 + tx)];
    __syncthreads();
#pragma unroll
    for (int i = 0; i < 32; i += 8)
      dst[(size_t)(c0 + ty + i) * R + (r0 + tx)] = f2bf(tbuf[tx][ty + i]);
    return;
  }
  // ---- compact (complement tail): rows[z][0..cnt)=active, [cnt..4096)=masked ----
  {
    int z = bid - 20480;
    if (t == 0) { cnt = 0; mcnt = 0; }
    __syncthreads();
    int* rz = rows + (size_t)z * 4096;
    for (int i = t; i < 4096; i += 256) {
      bool m = mask[(size_t)i * 16 + z] != 0;
      unsigned long long bal = __ballot(m);
      int lane = t & 63;
      int pa = __popcll(bal & ((1ull << lane) - 1ull));
      int ta = __popcll(bal);
      int base_a, base_m;
      if (lane == 0) { base_a = atomicAdd(&cnt, ta); base_m = atomicAdd(&mcnt, 64 - ta); }
      base_a = __shfl(base_a, 0);
      base_m = __shfl(base_m, 0);
      int pm = lane - pa;
      if (m) rz[base_a + pa] = i;
      else   rz[4095 - (base_m + pm)] = i;
    }
    __syncthreads();
    if (t == 0) counts[z] = cnt;
  }
}

// ================= GEMM: r9 structure + LDS-bounce vectorized epilogue =================
// 128x128 tile, BK=64, 256 threads (4 waves, 2x2 of 64x64), 1-phase __syncthreads loop.
__device__ __forceinline__ void stage_tile(const unsigned short* __restrict__ src,
                                           size_t row_stride, int row0, int k0,
                                           unsigned short* lds) {
  int t = threadIdx.x;
  int lane = t & 63;
  int w = t >> 6;
#pragma unroll
  for (int i = 0; i < 4; ++i) {
    int chunk = w * 4 + i;
    int row = chunk * 8 + (lane >> 3);
    int glog = (lane & 7) ^ (row & 7);
    const unsigned short* g = src + (size_t)(row0 + row) * row_stride + (size_t)(k0 + glog * 8);
    __builtin_amdgcn_global_load_lds((const __attribute__((address_space(1))) unsigned int*)g,
                                     (__attribute__((address_space(3))) unsigned int*)(lds + chunk * 512),
                                     16, 0, 0);
  }
}

__device__ __forceinline__ void stage_tile_gather(const unsigned short* __restrict__ src,
                                                  const int* __restrict__ rowsS, int k0,
                                                  unsigned short* lds) {
  int t = threadIdx.x;
  int lane = t & 63;
  int w = t >> 6;
#pragma unroll
  for (int i = 0; i < 4; ++i) {
    int chunk = w * 4 + i;
    int row = chunk * 8 + (lane >> 3);
    int glog = (lane & 7) ^ (row & 7);
    const unsigned short* g = src + (size_t)rowsS[row] * 1024 + (size_t)(k0 + glog * 8);
    __builtin_amdgcn_global_load_lds((const __attribute__((address_space(1))) unsigned int*)g,
                                     (__attribute__((address_space(3))) unsigned int*)(lds + chunk * 512),
                                     16, 0, 0);
  }
}

__device__ __forceinline__ bf16x8 read_frag(const unsigned short* lds, int row, int gb) {
  int phys = (row * 128 + gb) ^ ((row & 7) << 4);
  return *(const bf16x8*)((const char*)lds + phys);
}

// MODE 0: pre[z][r][m] (bf16) = x_bf[rows[z][r]] . A_t[z]^T   (K=1024)
// MODE 1: inner[rows[z][r]][z][h] = pre[z][r] . B_t[z]^T (K=512) + zero-fill masked tail rows
template <int MODE>
__global__ __launch_bounds__(256)
void moe_gemm_kernel(const unsigned short* __restrict__ X,
                     const unsigned short* __restrict__ W,
                     unsigned short* __restrict__ pre_out,
                     float* __restrict__ inner_out,
                     const int* __restrict__ rows,
                     const int* __restrict__ counts) {
  const int z = blockIdx.z;
  const int cnt = counts[z];
  const int tb = blockIdx.y * 128;
  const int tn = blockIdx.x * 128;
  const int t = threadIdx.x;

  if (MODE == 0 && tb >= cnt) return;

  // staging LDS reused as epilogue scratch (union) -> ~33KB/block, still 4 blocks/CU
  __shared__ union ShMem {
    struct { unsigned short Xs[128 * 64]; unsigned short Ws[128 * 64]; } st;  // 32KB
    float fs[64][132];           // 33.8KB, MODE1 epilogue (pad 4 f32)
    unsigned short hs[64][136];  // 17.4KB, MODE0 epilogue (pad 8 bf16)
  } sh;
  __shared__ int rowsS[128];
  unsigned short* Xs = sh.st.Xs;
  unsigned short* Ws = sh.st.Ws;

  if (t < 128) rowsS[t] = rows[(size_t)z * 4096 + tb + t];
  __syncthreads();

  if (MODE == 1 && tb >= cnt) {  // pure zero-fill block (masked rows)
    const float4 z4 = {0.f, 0.f, 0.f, 0.f};
#pragma unroll
    for (int it = 0; it < 16; ++it) {
      int rl = it * 8 + (t >> 5);
      int b = rowsS[rl];
      ((float4*)(inner_out + (size_t)b * (16 * 1024) + (size_t)z * 1024 + tn))[t & 31] = z4;
    }
    return;
  }

  const int lane = t & 63;
  const int wv = t >> 6;
  const int wr = (wv >> 1) * 64;
  const int wc = (wv & 1) * 64;
  const int fr = lane & 15;
  const int fg = lane >> 4;

  const unsigned short* Xbase;
  const unsigned short* Wbase;
  size_t xstride, wstride;
  int nkt;
  if (MODE == 0) {
    Xbase = X;                            xstride = 1024;   // gathered
    Wbase = W + (size_t)z * 512 * 1024;   wstride = 1024;
    nkt = 16;
  } else {
    Xbase = X + (size_t)z * 4096 * 512;   xstride = 512;    // compact-contiguous
    Wbase = W + (size_t)z * 1024 * 512;   wstride = 512;
    nkt = 8;
  }

  f32x4 acc[4][4] = {};

  for (int kt = 0; kt < nkt; ++kt) {
    if (kt) __syncthreads();
    if (MODE == 0) stage_tile_gather(Xbase, rowsS, kt * 64, Xs);
    else           stage_tile(Xbase, xstride, tb, kt * 64, Xs);
    stage_tile(Wbase, wstride, tn, kt * 64, Ws);
    __syncthreads();
#pragma unroll
    for (int kk = 0; kk < 2; ++kk) {
      const int gb = kk * 64 + fg * 16;
      bf16x8 xf[4], wf[4];
#pragma unroll
      for (int i = 0; i < 4; ++i) {
        xf[i] = read_frag(Xs, wr + i * 16 + fr, gb);
        wf[i] = read_frag(Ws, wc + i * 16 + fr, gb);
      }
#pragma unroll
      for (int mi = 0; mi < 4; ++mi)
#pragma unroll
        for (int ni = 0; ni < 4; ++ni)
          acc[mi][ni] = __builtin_amdgcn_mfma_f32_16x16x32_bf16(xf[mi], wf[ni], acc[mi][ni], 0, 0, 0);
    }
  }

  __syncthreads();  // all waves done reading Xs/Ws before scratch reuse

  // ---- LDS-bounce epilogue: two half-tiles of 64 rows, vectorized coalesced stores ----
  // acc C/D layout: col = lane&15, row = (lane>>4)*4 + j  (within the wave's 64x64 quadrant)
  if (MODE == 0) {
#pragma unroll
    for (int H = 0; H < 2; ++H) {
      if ((wv >> 1) == H) {
#pragma unroll
        for (int mi = 0; mi < 4; ++mi)
#pragma unroll
          for (int j = 0; j < 4; ++j)
#pragma unroll
            for (int ni = 0; ni < 4; ++ni)
              sh.hs[mi * 16 + fg * 4 + j][wc + ni * 16 + fr] = f2bf(acc[mi][ni][j]);
      }
      __syncthreads();
#pragma unroll
      for (int i = 0; i < 4; ++i) {
        int s = t + 256 * i;           // 1024 chunks of 16B: 64 rows x 16
        int row = s >> 4, c8 = s & 15;
        int rl = H * 64 + row;
        size_t rowbase = (size_t)z * 4096 * 512 + (size_t)(tb + rl) * 512 + tn;
        ((bf16x8*)(pre_out + rowbase))[c8] = *(const bf16x8*)&sh.hs[row][c8 * 8];
      }
      __syncthreads();
    }
  } else {
#pragma unroll
    for (int H = 0; H < 2; ++H) {
      if ((wv >> 1) == H) {
#pragma unroll
        for (int mi = 0; mi < 4; ++mi)
#pragma unroll
          for (int j = 0; j < 4; ++j)
#pragma unroll
            for (int ni = 0; ni < 4; ++ni)
              sh.fs[mi * 16 + fg * 4 + j][wc + ni * 16 + fr] = acc[mi][ni][j];
      }
      __syncthreads();
#pragma unroll
      for (int i = 0; i < 8; ++i) {
        int s = t + 256 * i;           // 2048 chunks of 16B: 64 rows x 32
        int row = s >> 5, c4 = s & 31;
        int rl = H * 64 + row;
        int b = rowsS[rl];
        float4 v = {0.f, 0.f, 0.f, 0.f};
        if (tb + rl < cnt) v = *(const float4*)&sh.fs[row][c4 * 4];
        ((float4*)(inner_out + (size_t)b * (16 * 1024) + (size_t)z * 1024 + tn))[c4] = v;
      }
      __syncthreads();
    }
  }
}

// ---- out[b] = bias + sum_{k: mask[b][k]} inner[b][k] ----
__global__ __launch_bounds__(256)
void reduce_kernel(const float* __restrict__ inner, const float* __restrict__ bias,
                   const int* __restrict__ mask, float* __restrict__ out) {
  int b = blockIdx.x;
  int t = threadIdx.x;
  __shared__ int mrow[16];
  if (t < 16) mrow[t] = mask[(size_t)b * 16 + t];
  __syncthreads();
  float4 s = ((const float4*)bias)[t];
  const float4* ip = (const float4*)(inner + (size_t)b * (16 * 1024)) + t;
#pragma unroll
  for (int k = 0; k < 16; ++k) {
    if (mrow[k]) {
      float4 v = ip[(size_t)k * 256];
      s.x += v.x; s.y += v.y; s.z += v.z; s.w += v.w;
    }
  }
  ((float4*)out)[(size_t)b * 256 + t] = s;
}

extern "C" void kernel_launch(void* const* d_in, const int* in_sizes, int n_in,
                              void* d_out, int out_size, void* d_ws, size_t ws_size,
                              hipStream_t stream) {
  const float* x    = (const float*)d_in[0];
  const int*   mask = (const int*)d_in[1];
  const float* A    = (const float*)d_in[2];
  const float* B    = (const float*)d_in[3];
  const float* bias = (const float*)d_in[4];

  float* out   = (float*)d_out;
  float* inner = (float*)d_out + (size_t)4096 * 1024;

  // ws layout: x_bf 8MiB | A_t 16MiB | B_t 16MiB | pre 64MiB | rows 256KiB | counts
  if (ws_size < 109314112ull) return;
  char* ws = (char*)d_ws;
  unsigned short* x_bf = (unsigned short*)ws;
  unsigned short* A_t  = (unsigned short*)(ws + ((size_t)8 << 20));
  unsigned short* B_t  = (unsigned short*)(ws + ((size_t)24 << 20));
  unsigned short* pre  = (unsigned short*)(ws + ((size_t)40 << 20));
  int* rows            = (int*)(ws + ((size_t)104 << 20));
  int* counts          = (int*)(ws + ((size_t)104 << 20) + 262144);

  prep_kernel<<<20496, 256, 0, stream>>>(x, x_bf, A, A_t, B, B_t, mask, rows, counts);

  moe_gemm_kernel<0><<<dim3(4, 32, 16), 256, 0, stream>>>(x_bf, A_t, pre, nullptr, rows, counts);
  moe_gemm_kernel<1><<<dim3(8, 32, 16), 256, 0, stream>>>(pre, B_t, nullptr, inner, rows, counts);

  reduce_kernel<<<4096, 256, 0, stream>>>(inner, bias, mask, out);
}

// Round 11
// 189.612 us; speedup vs baseline: 1.1429x; 1.1429x over previous
//
#include <hip/hip_runtime.h>

typedef __attribute__((ext_vector_type(8))) short bf16x8;
typedef __attribute__((ext_vector_type(4))) float f32x4;

__device__ __forceinline__ unsigned short f2bf(float f) {
  union { float f; unsigned u; } v; v.f = f;
  unsigned r = v.u + 0x7fffu + ((v.u >> 16) & 1u);
  return (unsigned short)(r >> 16);
}

// ================= merged prep: cvt_x | transpose A | transpose B | compact =================
__global__ __launch_bounds__(256)
void prep_kernel(const float* __restrict__ x, unsigned short* __restrict__ x_bf,
                 const float* __restrict__ A, unsigned short* __restrict__ A_t,
                 const float* __restrict__ B, unsigned short* __restrict__ B_t,
                 const int* __restrict__ mask, int* __restrict__ rows,
                 int* __restrict__ counts) {
  __shared__ float tbuf[32][33];
  __shared__ int cnt, mcnt;
  const int bid = blockIdx.x;
  const int t = threadIdx.x;

  if (bid < 4096) {  // ---- cvt_x: f32 -> bf16 ----
    int i = bid * 256 + t;
    float4 v = ((const float4*)x)[i];
    ushort4 o; o.x = f2bf(v.x); o.y = f2bf(v.y); o.z = f2bf(v.z); o.w = f2bf(v.w);
    ((ushort4*)x_bf)[i] = o;
    return;
  }
  if (bid < 20480) {  // ---- transpose+convert A or B ----
    const float* in; unsigned short* out; int R, C, cx, ry, z;
    if (bid < 12288) {  // A: [16][1024][512] -> [16][512][1024]
      int local = (bid - 4096) & 511; z = (bid - 4096) >> 9;
      R = 1024; C = 512; cx = local & 15; ry = local >> 4;
      in = A; out = A_t;
    } else {            // B: [16][512][1024] -> [16][1024][512]
      int local = (bid - 12288) & 511; z = (bid - 12288) >> 9;
      R = 512; C = 1024; cx = local & 31; ry = local >> 5;
      in = B; out = B_t;
    }
    size_t eo = (size_t)z * R * C;
    const float* src = in + eo;
    unsigned short* dst = out + eo;
    int c0 = cx * 32, r0 = ry * 32;
    int tx = t & 31, ty = t >> 5;  // (32,8)
#pragma unroll
    for (int i = 0; i < 32; i += 8)
      tbuf[ty + i][tx] = src[(size_t)(r0 + ty + i) * C + (c0 + tx)];
    __syncthreads();
#pragma unroll
    for (int i = 0; i < 32; i += 8)
      dst[(size_t)(c0 + ty + i) * R + (r0 + tx)] = f2bf(tbuf[tx][ty + i]);
    return;
  }
  // ---- compact (complement tail): rows[z][0..cnt)=active, [cnt..4096)=masked ----
  {
    int z = bid - 20480;
    if (t == 0) { cnt = 0; mcnt = 0; }
    __syncthreads();
    int* rz = rows + (size_t)z * 4096;
    for (int i = t; i < 4096; i += 256) {
      bool m = mask[(size_t)i * 16 + z] != 0;
      unsigned long long bal = __ballot(m);
      int lane = t & 63;
      int pa = __popcll(bal & ((1ull << lane) - 1ull));
      int ta = __popcll(bal);
      int base_a, base_m;
      if (lane == 0) { base_a = atomicAdd(&cnt, ta); base_m = atomicAdd(&mcnt, 64 - ta); }
      base_a = __shfl(base_a, 0);
      base_m = __shfl(base_m, 0);
      int pm = lane - pa;
      if (m) rz[base_a + pa] = i;
      else   rz[4095 - (base_m + pm)] = i;
    }
    __syncthreads();
    if (t == 0) counts[z] = cnt;
  }
}

// ================= GEMM: exact r9 structure + isolated T1 XCD-chunk swizzle =================
// 128x128 tile, BK=64, 256 threads (4 waves, 2x2 of 64x64), 1-phase __syncthreads loop.
__device__ __forceinline__ void stage_tile(const unsigned short* __restrict__ src,
                                           size_t row_stride, int row0, int k0,
                                           unsigned short* lds) {
  int t = threadIdx.x;
  int lane = t & 63;
  int w = t >> 6;
#pragma unroll
  for (int i = 0; i < 4; ++i) {
    int chunk = w * 4 + i;
    int row = chunk * 8 + (lane >> 3);
    int glog = (lane & 7) ^ (row & 7);
    const unsigned short* g = src + (size_t)(row0 + row) * row_stride + (size_t)(k0 + glog * 8);
    __builtin_amdgcn_global_load_lds((const __attribute__((address_space(1))) unsigned int*)g,
                                     (__attribute__((address_space(3))) unsigned int*)(lds + chunk * 512),
                                     16, 0, 0);
  }
}

__device__ __forceinline__ void stage_tile_gather(const unsigned short* __restrict__ src,
                                                  const int* __restrict__ rowsS, int k0,
                                                  unsigned short* lds) {
  int t = threadIdx.x;
  int lane = t & 63;
  int w = t >> 6;
#pragma unroll
  for (int i = 0; i < 4; ++i) {
    int chunk = w * 4 + i;
    int row = chunk * 8 + (lane >> 3);
    int glog = (lane & 7) ^ (row & 7);
    const unsigned short* g = src + (size_t)rowsS[row] * 1024 + (size_t)(k0 + glog * 8);
    __builtin_amdgcn_global_load_lds((const __attribute__((address_space(1))) unsigned int*)g,
                                     (__attribute__((address_space(3))) unsigned int*)(lds + chunk * 512),
                                     16, 0, 0);
  }
}

__device__ __forceinline__ bf16x8 read_frag(const unsigned short* lds, int row, int gb) {
  int phys = (row * 128 + gb) ^ ((row & 7) << 4);
  return *(const bf16x8*)((const char*)lds + phys);
}

// MODE 0: pre[z][r][m] (bf16) = x_bf[rows[z][r]] . A_t[z]^T   (K=1024)
// MODE 1: inner[rows[z][r]][z][h] = pre[z][r] . B_t[z]^T (K=512) + zero-fill masked tail rows
template <int MODE>
__global__ __launch_bounds__(256)
void moe_gemm_kernel(const unsigned short* __restrict__ X,
                     const unsigned short* __restrict__ W,
                     unsigned short* __restrict__ pre_out,
                     float* __restrict__ inner_out,
                     const int* __restrict__ rows,
                     const int* __restrict__ counts) {
  // ---- T1: bijective XCD-chunk swizzle (nwg divisible by 8) ----
  // HW dispatches original ids round-robin over 8 XCDs; remap so XCD k gets a
  // contiguous work chunk (z in high bits -> each XCD owns 2 experts -> weights L2-resident).
  const int gx = gridDim.x, gy = gridDim.y;
  {
    int lin = blockIdx.x + gx * (blockIdx.y + gy * blockIdx.z);
    int cpx = (gx * gy * gridDim.z) >> 3;
    lin = (lin & 7) * cpx + (lin >> 3);
    // unpack: bx fastest, then by, then z
    int bx = lin % gx; lin /= gx;
    int by = lin % gy; lin /= gy;
    const int z = lin;
    const int cnt = counts[z];
    const int tb = by * 128;
    const int tn = bx * 128;
    const int t = threadIdx.x;

    if (MODE == 0 && tb >= cnt) return;

    __shared__ unsigned short Xs[128 * 64];
    __shared__ unsigned short Ws[128 * 64];
    __shared__ int rowsS[128];

    if (t < 128) rowsS[t] = rows[(size_t)z * 4096 + tb + t];
    __syncthreads();

    if (MODE == 1 && tb >= cnt) {  // pure zero-fill block (masked rows)
      const float4 z4 = {0.f, 0.f, 0.f, 0.f};
#pragma unroll
      for (int it = 0; it < 16; ++it) {
        int rl = it * 8 + (t >> 5);
        int b = rowsS[rl];
        ((float4*)(inner_out + (size_t)b * (16 * 1024) + (size_t)z * 1024 + tn))[t & 31] = z4;
      }
      return;
    }

    const int lane = t & 63;
    const int wv = t >> 6;
    const int wr = (wv >> 1) * 64;
    const int wc = (wv & 1) * 64;
    const int fr = lane & 15;
    const int fg = lane >> 4;

    const unsigned short* Xbase;
    const unsigned short* Wbase;
    size_t xstride, wstride;
    int nkt;
    if (MODE == 0) {
      Xbase = X;                            xstride = 1024;   // gathered
      Wbase = W + (size_t)z * 512 * 1024;   wstride = 1024;
      nkt = 16;
    } else {
      Xbase = X + (size_t)z * 4096 * 512;   xstride = 512;    // compact-contiguous
      Wbase = W + (size_t)z * 1024 * 512;   wstride = 512;
      nkt = 8;
    }

    f32x4 acc[4][4] = {};

    for (int kt = 0; kt < nkt; ++kt) {
      if (kt) __syncthreads();
      if (MODE == 0) stage_tile_gather(Xbase, rowsS, kt * 64, Xs);
      else           stage_tile(Xbase, xstride, tb, kt * 64, Xs);
      stage_tile(Wbase, wstride, tn, kt * 64, Ws);
      __syncthreads();
#pragma unroll
      for (int kk = 0; kk < 2; ++kk) {
        const int gb = kk * 64 + fg * 16;
        bf16x8 xf[4], wf[4];
#pragma unroll
        for (int i = 0; i < 4; ++i) {
          xf[i] = read_frag(Xs, wr + i * 16 + fr, gb);
          wf[i] = read_frag(Ws, wc + i * 16 + fr, gb);
        }
#pragma unroll
        for (int mi = 0; mi < 4; ++mi)
#pragma unroll
          for (int ni = 0; ni < 4; ++ni)
            acc[mi][ni] = __builtin_amdgcn_mfma_f32_16x16x32_bf16(xf[mi], wf[ni], acc[mi][ni], 0, 0, 0);
      }
    }

    // C/D layout: col = lane&15, row = (lane>>4)*4 + j
    if (MODE == 0) {
#pragma unroll
      for (int mi = 0; mi < 4; ++mi) {
#pragma unroll
        for (int j = 0; j < 4; ++j) {
          int rl = wr + mi * 16 + fg * 4 + j;
          size_t rowbase = (size_t)z * 4096 * 512 + (size_t)(tb + rl) * 512;
#pragma unroll
          for (int ni = 0; ni < 4; ++ni) {
            int m = tn + wc + ni * 16 + fr;
            pre_out[rowbase + m] = f2bf(acc[mi][ni][j]);  // padded slots: finite garbage, discarded
          }
        }
      }
    } else {
#pragma unroll
      for (int mi = 0; mi < 4; ++mi) {
#pragma unroll
        for (int j = 0; j < 4; ++j) {
          int rl = wr + mi * 16 + fg * 4 + j;
          int b = rowsS[rl];
          size_t rowbase = (size_t)b * (16 * 1024) + (size_t)z * 1024;
          if (tb + rl < cnt) {
#pragma unroll
            for (int ni = 0; ni < 4; ++ni) {
              int h = tn + wc + ni * 16 + fr;
              inner_out[rowbase + h] = acc[mi][ni][j];
            }
          } else {  // boundary block: masked rows -> zeros
#pragma unroll
            for (int ni = 0; ni < 4; ++ni) {
              int h = tn + wc + ni * 16 + fr;
              inner_out[rowbase + h] = 0.f;
            }
          }
        }
      }
    }
  }
}

// ---- out[b] = bias + sum_{k: mask[b][k]} inner[b][k] ----
__global__ __launch_bounds__(256)
void reduce_kernel(const float* __restrict__ inner, const float* __restrict__ bias,
                   const int* __restrict__ mask, float* __restrict__ out) {
  int b = blockIdx.x;
  int t = threadIdx.x;
  __shared__ int mrow[16];
  if (t < 16) mrow[t] = mask[(size_t)b * 16 + t];
  __syncthreads();
  float4 s = ((const float4*)bias)[t];
  const float4* ip = (const float4*)(inner + (size_t)b * (16 * 1024)) + t;
#pragma unroll
  for (int k = 0; k < 16; ++k) {
    if (mrow[k]) {
      float4 v = ip[(size_t)k * 256];
      s.x += v.x; s.y += v.y; s.z += v.z; s.w += v.w;
    }
  }
  ((float4*)out)[(size_t)b * 256 + t] = s;
}

extern "C" void kernel_launch(void* const* d_in, const int* in_sizes, int n_in,
                              void* d_out, int out_size, void* d_ws, size_t ws_size,
                              hipStream_t stream) {
  const float* x    = (const float*)d_in[0];
  const int*   mask = (const int*)d_in[1];
  const float* A    = (const float*)d_in[2];
  const float* B    = (const float*)d_in[3];
  const float* bias = (const float*)d_in[4];

  float* out   = (float*)d_out;
  float* inner = (float*)d_out + (size_t)4096 * 1024;

  // ws layout: x_bf 8MiB | A_t 16MiB | B_t 16MiB | pre 64MiB | rows 256KiB | counts
  if (ws_size < 109314112ull) return;
  char* ws = (char*)d_ws;
  unsigned short* x_bf = (unsigned short*)ws;
  unsigned short* A_t  = (unsigned short*)(ws + ((size_t)8 << 20));
  unsigned short* B_t  = (unsigned short*)(ws + ((size_t)24 << 20));
  unsigned short* pre  = (unsigned short*)(ws + ((size_t)40 << 20));
  int* rows            = (int*)(ws + ((size_t)104 << 20));
  int* counts          = (int*)(ws + ((size_t)104 << 20) + 262144);

  prep_kernel<<<20496, 256, 0, stream>>>(x, x_bf, A, A_t, B, B_t, mask, rows, counts);

  moe_gemm_kernel<0><<<dim3(4, 32, 16), 256, 0, stream>>>(x_bf, A_t, pre, nullptr, rows, counts);
  moe_gemm_kernel<1><<<dim3(8, 32, 16), 256, 0, stream>>>(pre, B_t, nullptr, inner, rows, counts);

  reduce_kernel<<<4096, 256, 0, stream>>>(inner, bias, mask, out);
}